// Round 1
// baseline (21.682 us; speedup 1.0000x reference)
//
#include <hip/hip_runtime.h>

// PrimitiveCollisionCost: B=16 H=64 L=12 S=8 W=256
// inputs: link_pos_seq (N,L,3) f32, link_rot_seq (N,L,3,3) f32,
//         link_spheres (L,S,4) f32, world_spheres (W,4) f32, weight scalar f32
// output: cost (N,) f32, N = B*H = 1024

#define NL 12
#define NS 8
#define NW 256

__global__ __launch_bounds__(256) void pcc_kernel(
    const float* __restrict__ pos,    // (N, L, 3)
    const float* __restrict__ rot,    // (N, L, 9)
    const float* __restrict__ lsph,   // (L, S, 4)
    const float* __restrict__ wsph,   // (W, 4)
    const float* __restrict__ weight, // scalar
    float* __restrict__ out)          // (N)
{
    const int n    = blockIdx.x;
    const int tid  = threadIdx.x;
    const int lane = tid & 63;
    const int wave = tid >> 6;   // 0..3

    // Each lane owns 4 world spheres (w = lane + 64*k), kept in registers.
    float4 ws[4];
#pragma unroll
    for (int k = 0; k < 4; ++k)
        ws[k] = reinterpret_cast<const float4*>(wsph)[lane + 64 * k];

    __shared__ float partial[4];

    float acc = 0.0f;
#pragma unroll
    for (int li = 0; li < 3; ++li) {
        const int l = wave * 3 + li;
        const float* r = rot + ((size_t)n * NL + l) * 9;
        const float* p = pos + ((size_t)n * NL + l) * 3;
        const float r00 = r[0], r01 = r[1], r02 = r[2];
        const float r10 = r[3], r11 = r[4], r12 = r[5];
        const float r20 = r[6], r21 = r[7], r22 = r[8];
        const float px = p[0], py = p[1], pz = p[2];

        float m = -1e30f;
#pragma unroll
        for (int s = 0; s < NS; ++s) {
            const float4 ls = reinterpret_cast<const float4*>(lsph)[l * NS + s];
            // center_i = sum_j rot[i][j] * sph[j] + pos_i
            const float cx = r00 * ls.x + r01 * ls.y + r02 * ls.z + px;
            const float cy = r10 * ls.x + r11 * ls.y + r12 * ls.z + py;
            const float cz = r20 * ls.x + r21 * ls.y + r22 * ls.z + pz;
            const float rr = ls.w;
#pragma unroll
            for (int k = 0; k < 4; ++k) {
                const float dx = cx - ws[k].x;
                const float dy = cy - ws[k].y;
                const float dz = cz - ws[k].z;
                const float dist = sqrtf(dx * dx + dy * dy + dz * dz);
                m = fmaxf(m, ws[k].w - dist + rr);
            }
        }
        // wave-wide max reduce (64 lanes)
#pragma unroll
        for (int off = 1; off < 64; off <<= 1)
            m = fmaxf(m, __shfl_xor(m, off));
        // d = clip(m + 0.1, 0, 0.2) / 0.25
        acc += fminf(fmaxf(m + 0.1f, 0.0f), 0.2f) * 4.0f;
    }

    if (lane == 0) partial[wave] = acc;
    __syncthreads();
    if (tid == 0)
        out[n] = weight[0] * (partial[0] + partial[1] + partial[2] + partial[3]);
}

extern "C" void kernel_launch(void* const* d_in, const int* in_sizes, int n_in,
                              void* d_out, int out_size, void* d_ws, size_t ws_size,
                              hipStream_t stream) {
    const float* pos    = (const float*)d_in[0];
    const float* rot    = (const float*)d_in[1];
    const float* lsph   = (const float*)d_in[2];
    const float* wsph   = (const float*)d_in[3];
    const float* weight = (const float*)d_in[4];
    float* out = (float*)d_out;

    const int N = out_size; // 1024
    pcc_kernel<<<N, 256, 0, stream>>>(pos, rot, lsph, wsph, weight, out);
}

// Round 6
// 15.321 us; speedup vs baseline: 1.4152x; 1.4152x over previous
//
#include <hip/hip_runtime.h>

// PrimitiveCollisionCost: B=16 H=64 L=12 S=8 W=256
// inputs: link_pos_seq (N,L,3) f32, link_rot_seq (N,L,3,3) f32,
//         link_spheres (L,S,4) f32, world_spheres (W,4) f32, weight scalar f32
// output: cost (N,) f32, N = B*H = 1024

#define NL 12
#define NS 8

__device__ __forceinline__ float fast_sqrtf(float x) {
    // single v_sqrt_f32 (~1 ulp), skips libm's IEEE fixup sequence
    return __builtin_amdgcn_sqrtf(x);
}

__global__ __launch_bounds__(256) void pcc_kernel(
    const float* __restrict__ pos,    // (N, L, 3)
    const float* __restrict__ rot,    // (N, L, 9)
    const float* __restrict__ lsph,   // (L, S, 4)
    const float* __restrict__ wsph,   // (W, 4)
    const float* __restrict__ weight, // scalar
    float* __restrict__ out)          // (N)
{
    const int n    = blockIdx.x;
    const int tid  = threadIdx.x;
    const int lane = tid & 63;
    const int wave = tid >> 6;   // 0..3, wave w owns links 3w..3w+2

    // Each lane owns 4 world spheres (w = lane + 64*k), kept in registers.
    const float4* wsph4 = reinterpret_cast<const float4*>(wsph);
    const float4 ws0 = wsph4[lane];
    const float4 ws1 = wsph4[lane + 64];
    const float4 ws2 = wsph4[lane + 128];
    const float4 ws3 = wsph4[lane + 192];

    const float4* lsph4 = reinterpret_cast<const float4*>(lsph);

    float m[3];
    m[0] = m[1] = m[2] = -1e30f;

#pragma unroll
    for (int li = 0; li < 3; ++li) {
        const int l = wave * 3 + li;
        const float* r = rot + ((size_t)n * NL + l) * 9;
        const float* p = pos + ((size_t)n * NL + l) * 3;
        const float r00 = r[0], r01 = r[1], r02 = r[2];
        const float r10 = r[3], r11 = r[4], r12 = r[5];
        const float r20 = r[6], r21 = r[7], r22 = r[8];
        const float px = p[0], py = p[1], pz = p[2];

#pragma unroll
        for (int s = 0; s < NS; ++s) {
            const float4 ls = lsph4[l * NS + s];
            // center_i = sum_j rot[i][j] * sph[j] + pos_i
            const float cx = r00 * ls.x + r01 * ls.y + r02 * ls.z + px;
            const float cy = r10 * ls.x + r11 * ls.y + r12 * ls.z + py;
            const float cz = r20 * ls.x + r21 * ls.y + r22 * ls.z + pz;
            const float rr = ls.w;

            float dx0 = cx - ws0.x, dy0 = cy - ws0.y, dz0 = cz - ws0.z;
            float dx1 = cx - ws1.x, dy1 = cy - ws1.y, dz1 = cz - ws1.z;
            float dx2 = cx - ws2.x, dy2 = cy - ws2.y, dz2 = cz - ws2.z;
            float dx3 = cx - ws3.x, dy3 = cy - ws3.y, dz3 = cz - ws3.z;

            const float v0 = ws0.w + rr - fast_sqrtf(dx0*dx0 + dy0*dy0 + dz0*dz0);
            const float v1 = ws1.w + rr - fast_sqrtf(dx1*dx1 + dy1*dy1 + dz1*dz1);
            const float v2 = ws2.w + rr - fast_sqrtf(dx2*dx2 + dy2*dy2 + dz2*dz2);
            const float v3 = ws3.w + rr - fast_sqrtf(dx3*dx3 + dy3*dy3 + dz3*dz3);

            // tree max: depth 2 instead of serial chain
            const float t = fmaxf(fmaxf(v0, v1), fmaxf(v2, v3));
            m[li] = fmaxf(m[li], t);
        }
    }

    // three independent 64-lane butterflies, interleaved for ILP
#pragma unroll
    for (int off = 1; off < 64; off <<= 1) {
        m[0] = fmaxf(m[0], __shfl_xor(m[0], off));
        m[1] = fmaxf(m[1], __shfl_xor(m[1], off));
        m[2] = fmaxf(m[2], __shfl_xor(m[2], off));
    }

    // d = clip(m + 0.1, 0, 0.2) / 0.25  (== clamp * 4)
    float acc = fminf(fmaxf(m[0] + 0.1f, 0.0f), 0.2f) * 4.0f
              + fminf(fmaxf(m[1] + 0.1f, 0.0f), 0.2f) * 4.0f
              + fminf(fmaxf(m[2] + 0.1f, 0.0f), 0.2f) * 4.0f;

    __shared__ float partial[4];
    if (lane == 0) partial[wave] = acc;
    __syncthreads();
    if (tid == 0)
        out[n] = weight[0] * (partial[0] + partial[1] + partial[2] + partial[3]);
}

extern "C" void kernel_launch(void* const* d_in, const int* in_sizes, int n_in,
                              void* d_out, int out_size, void* d_ws, size_t ws_size,
                              hipStream_t stream) {
    const float* pos    = (const float*)d_in[0];
    const float* rot    = (const float*)d_in[1];
    const float* lsph   = (const float*)d_in[2];
    const float* wsph   = (const float*)d_in[3];
    const float* weight = (const float*)d_in[4];
    float* out = (float*)d_out;

    const int N = out_size; // 1024
    pcc_kernel<<<N, 256, 0, stream>>>(pos, rot, lsph, wsph, weight, out);
}